// Round 2
// baseline (507.125 us; speedup 1.0000x reference)
//
#include <hip/hip_runtime.h>

// Problem: radius-graph edge computation on N=8192 points in 2D, periodic box L=1.
// Outputs (concatenated in d_out, fp32):
//   [0 .. N*N)      dist[i][j] = || minimum_image(x[j] - x[i]) ||
//   [N*N .. 2*N*N)  within[i][j] = (dist < 0.1) && (i != j)  as 0.0/1.0
//
// Memory-bound on the 536 MB of output writes; input x (64 KB) is cache-resident.

constexpr int   N    = 8192;
constexpr float R0   = 0.1f;
// L = 1.0 -> minimum image is dr -= rintf(dr)

__global__ __launch_bounds__(256)
void radiusgraph_kernel(const float* __restrict__ x,
                        float* __restrict__ dist,
                        float* __restrict__ mask) {
    const int i  = blockIdx.y;                               // row
    const int j0 = (blockIdx.x * 256 + threadIdx.x) * 4;     // 4 columns per thread

    // broadcast read (all lanes same addr -> one transaction, L1-hit)
    const float2 xi = *reinterpret_cast<const float2*>(x + 2 * (size_t)i);

    // 4 consecutive float2 points = two float4 coalesced loads (L1/L2-hit)
    const float4 a = *reinterpret_cast<const float4*>(x + 2 * (size_t)j0);
    const float4 b = *reinterpret_cast<const float4*>(x + 2 * (size_t)j0 + 4);

    const float xs[4] = {a.x, a.z, b.x, b.z};
    const float ys[4] = {a.y, a.w, b.y, b.w};

    float4 dout, mout;
    float* dp = &dout.x;
    float* mp = &mout.x;

#pragma unroll
    for (int k = 0; k < 4; ++k) {
        float dx = xs[k] - xi.x;
        float dy = ys[k] - xi.y;
        dx -= rintf(dx);          // minimum image, L=1 (v_rndne_f32, half-to-even like jnp.round)
        dy -= rintf(dy);
        const float d = sqrtf(dx * dx + dy * dy);
        dp[k] = d;
        mp[k] = (d < R0 && (j0 + k) != i) ? 1.0f : 0.0f;
    }

    const size_t base = (size_t)i * N + j0;
    *reinterpret_cast<float4*>(dist + base) = dout;
    *reinterpret_cast<float4*>(mask + base) = mout;
}

extern "C" void kernel_launch(void* const* d_in, const int* in_sizes, int n_in,
                              void* d_out, int out_size, void* d_ws, size_t ws_size,
                              hipStream_t stream) {
    const float* x = (const float*)d_in[0];
    float* out = (float*)d_out;
    float* dist = out;
    float* mask = out + (size_t)N * N;

    dim3 grid(N / (256 * 4), N);   // (8, 8192) blocks
    radiusgraph_kernel<<<grid, dim3(256), 0, stream>>>(x, dist, mask);
}